// Round 2
// baseline (321.141 us; speedup 1.0000x reference)
//
#include <hip/hip_runtime.h>
#include <math.h>

// NeRF volume rendering: N=65536 rays, S=192 samples.
// One wave (64 lanes) per ray; 3 sequential chunks of 64 samples.
// R2: all cross-lane ops via VALU DPP (update_dpp) instead of ds_bpermute
// shuffles -- the R1 profile showed both HBM (30%) and VALU (27%) idle with
// 54 DS-pipe ops per ray forming the critical path.

constexpr int kRays = 65536;
constexpr int kS = 192;

// update_dpp: result = (dest lane enabled by RM/BM) ? src[dpp-mapped lane] : old
// (bound_ctrl=false => invalid source lanes also yield old)
template <int CTRL, int RM, int BM>
__device__ __forceinline__ float fdpp(float src, float old_) {
    int r = __builtin_amdgcn_update_dpp(__float_as_int(old_), __float_as_int(src),
                                        CTRL, RM, BM, false);
    return __int_as_float(r);
}

// Inclusive multiply prefix-scan across 64 lanes (VALU only).
__device__ __forceinline__ float wave_scan_mul_incl(float x) {
    x *= fdpp<0x111, 0xf, 0xf>(x, 1.0f);  // row_shr:1
    x *= fdpp<0x112, 0xf, 0xf>(x, 1.0f);  // row_shr:2
    x *= fdpp<0x114, 0xf, 0xf>(x, 1.0f);  // row_shr:4
    x *= fdpp<0x118, 0xf, 0xf>(x, 1.0f);  // row_shr:8  -> per-row(16) scan
    x *= fdpp<0x142, 0xa, 0xf>(x, 1.0f);  // row_bcast:15 -> rows 1,3 *= prev row total
    x *= fdpp<0x143, 0xc, 0xf>(x, 1.0f);  // row_bcast:31 -> rows 2,3 *= rows0-1 total
    return x;
}

// Full-wave add reduction; grand total valid in lanes 48..63 (use lane 63).
__device__ __forceinline__ float wave_reduce_add(float x) {
    x += fdpp<0x121, 0xf, 0xf>(x, 0.0f);  // row_ror:1
    x += fdpp<0x122, 0xf, 0xf>(x, 0.0f);  // row_ror:2
    x += fdpp<0x124, 0xf, 0xf>(x, 0.0f);  // row_ror:4
    x += fdpp<0x128, 0xf, 0xf>(x, 0.0f);  // row_ror:8  -> row totals everywhere
    x += fdpp<0x142, 0xa, 0xf>(x, 0.0f);  // rows 1,3 += prev row total
    x += fdpp<0x143, 0x8, 0xf>(x, 0.0f);  // row 3 += rows0-1 total
    return x;
}

__device__ __forceinline__ float bcast_lane(float x, int lane) {
    return __int_as_float(__builtin_amdgcn_readlane(__float_as_int(x), lane));
}

__global__ __launch_bounds__(256) void nerf_render_kernel(
    const float* __restrict__ rgb,      // [N, S, 3]
    const float* __restrict__ sigma,    // [N, S]
    const float* __restrict__ z_vals,   // [N, S]
    const float* __restrict__ rays_d,   // [N, 3]
    float* __restrict__ out)
{
    const int lane = threadIdx.x & 63;
    const int ray  = (blockIdx.x << 2) + (threadIdx.x >> 6);  // 4 waves/block

    float* __restrict__ rgb_map   = out;                                        // [N,3]
    float* __restrict__ depth_map = out + (size_t)kRays * 3;                    // [N]
    float* __restrict__ acc_map   = out + (size_t)kRays * 4;                    // [N]
    float* __restrict__ weights_o = out + (size_t)kRays * 5;                    // [N,S]
    float* __restrict__ disp_map  = out + (size_t)kRays * 5 + (size_t)kRays * kS;      // [N]
    float* __restrict__ trans_o   = out + (size_t)kRays * 6 + (size_t)kRays * kS;      // [N,S]
    float* __restrict__ alpha_o   = out + (size_t)kRays * 6 + (size_t)kRays * kS * 2;  // [N,S]

    const float dx = rays_d[ray * 3 + 0];
    const float dy = rays_d[ray * 3 + 1];
    const float dz = rays_d[ray * 3 + 2];
    const float nrm = sqrtf(dx * dx + dy * dy + dz * dz);

    const size_t base = (size_t)ray * kS;

    float carry = 1.0f;
    float sr = 0.f, sg = 0.f, sb = 0.f, sd = 0.f, sw = 0.f;

    #pragma unroll
    for (int c = 0; c < 3; ++c) {
        const int idx = c * 64 + lane;
        const float zc = z_vals[base + idx];
        float dist;
        if (idx < kS - 1) {
            dist = (z_vals[base + idx + 1] - zc) * nrm;  // neighbor line -> L1 hit
        } else {
            dist = 1e10f * nrm;
        }

        float s = sigma[base + idx];
        s = s > 0.f ? s : 0.f;                 // relu
        const float e = expf(-s * dist);
        const float alpha = 1.0f - e;
        const float om = 1.0f - alpha;         // match reference rounding exactly

        const float incl = wave_scan_mul_incl(om);
        float excl = fdpp<0x138, 0xf, 0xf>(incl, 1.0f);  // wave_shr:1, lane0 = 1.0

        const float trans = carry * excl;
        const float w = alpha * trans;

        trans_o[base + idx]   = trans;
        alpha_o[base + idx]   = alpha;
        weights_o[base + idx] = w;

        const size_t rb = (base + idx) * 3;
        sr += w * rgb[rb + 0];
        sg += w * rgb[rb + 1];
        sb += w * rgb[rb + 2];
        sd += w * zc;
        sw += w;

        carry *= bcast_lane(incl, 63);         // chunk total, scalar broadcast
    }

    sr = wave_reduce_add(sr);
    sg = wave_reduce_add(sg);
    sb = wave_reduce_add(sb);
    sd = wave_reduce_add(sd);
    sw = wave_reduce_add(sw);

    if (lane == 63) {                          // grand totals live in lane 63
        rgb_map[ray * 3 + 0] = sr;
        rgb_map[ray * 3 + 1] = sg;
        rgb_map[ray * 3 + 2] = sb;
        depth_map[ray] = sd;
        acc_map[ray]   = sw;
        const float q = fmaxf(1e-10f, sd / sw);
        disp_map[ray] = 1.0f / q;
    }
}

extern "C" void kernel_launch(void* const* d_in, const int* in_sizes, int n_in,
                              void* d_out, int out_size, void* d_ws, size_t ws_size,
                              hipStream_t stream) {
    const float* rgb    = (const float*)d_in[0];
    const float* sigma  = (const float*)d_in[1];
    const float* z_vals = (const float*)d_in[2];
    const float* rays_d = (const float*)d_in[3];
    float* out = (float*)d_out;

    const int blocks = kRays / 4;  // 4 rays per 256-thread block
    nerf_render_kernel<<<blocks, 256, 0, stream>>>(rgb, sigma, z_vals, rays_d, out);
}